// Round 8
// baseline (262.805 us; speedup 1.0000x reference)
//
#include <hip/hip_runtime.h>
#include <hip/hip_fp16.h>

#define NN 100000   // nodes
#define NE 3200000  // edges
#define NF 128      // in features
#define EM 20       // embed
#define NC 10       // classes
#define NG 64       // graphs

#define NB 782      // dst buckets of 128 nodes
#define CAPB 4608   // per-bucket capacity (mean 4096, +8 sigma)
#define T 4096      // edges per scatter block
#define SBLK 1024   // scatter block threads

// ---------------- bucketed counting-sort scatter (round-0 proven) ----------------
__global__ __launch_bounds__(SBLK) void k_scatter(
        const int* __restrict__ src, const int* __restrict__ dst,
        const float* __restrict__ w, int* __restrict__ gcursor,
        uint2* __restrict__ barr) {
    __shared__ unsigned int cnt[1024];
    __shared__ unsigned int off[1024];
    __shared__ unsigned int gbase[NB];
    __shared__ unsigned int wsum[16];
    __shared__ uint2 staged[T];
    __shared__ unsigned short bkt[T];
    int tid = threadIdx.x;
    long E0 = (long)blockIdx.x * T;
    int tot = (int)min((long)T, (long)NE - E0);
    cnt[tid] = 0;
    __syncthreads();
    // histogram; cache dst in VGPRs
    unsigned int dreg[T / SBLK];
#pragma unroll
    for (int k = 0; k < T / SBLK; ++k) {
        int e = k * SBLK + tid;
        dreg[k] = 0;
        if (e < tot) {
            dreg[k] = (unsigned)dst[E0 + e];
            atomicAdd(&cnt[dreg[k] >> 7], 1u);
        }
    }
    __syncthreads();
    // exclusive scan of cnt[0..1024) via wave shfl
    {
        int lane = tid & 63, wv = tid >> 6;
        unsigned int v = cnt[tid];
        unsigned int s = v;
#pragma unroll
        for (int o = 1; o < 64; o <<= 1) {
            unsigned int t = __shfl_up(s, o);
            if (lane >= o) s += t;
        }
        if (lane == 63) wsum[wv] = s;
        __syncthreads();
        if (tid == 0) {
            unsigned int a = 0;
#pragma unroll
            for (int i = 0; i < 16; ++i) { unsigned int t = wsum[i]; wsum[i] = a; a += t; }
        }
        __syncthreads();
        off[tid] = wsum[wv] + s - v;   // exclusive prefix
    }
    __syncthreads();
    // reserve global segments; reset cnt as running slot counter
    if (tid < NB) {
        unsigned int c = cnt[tid];
        gbase[tid] = c ? (unsigned int)atomicAdd(&gcursor[tid], (int)c) : 0u;
        cnt[tid] = 0;
    }
    __syncthreads();
    // stage records grouped by bucket
#pragma unroll
    for (int k = 0; k < T / SBLK; ++k) {
        int e = k * SBLK + tid;
        if (e < tot) {
            long ge = E0 + e;
            unsigned int d = dreg[k];
            unsigned int b = d >> 7;
            unsigned int slot = atomicAdd(&cnt[b], 1u);
            unsigned int pos = off[b] + slot;
            staged[pos] = make_uint2((((unsigned)src[ge]) << 7) | (d & 127u),
                                     __float_as_uint(w[ge]));
            bkt[pos] = (unsigned short)b;
        }
    }
    __syncthreads();
    // coalesced run-flush
    for (int i = tid; i < tot; i += SBLK) {
        unsigned int b = bkt[i];
        unsigned int gpos = gbase[b] + ((unsigned)i - off[b]);
        if (gpos < CAPB) barr[(size_t)b * CAPB + gpos] = staged[i];
    }
}

// ---------------- FUSED: weighted degree + xw prescale (v2: no x LDS tile) ----------------
// Round-7's 66KB xs tile capped occupancy at 2 blocks/CU (30%) -> latency-bound.
// v2: x rows read straight from global (L3-resident; 4 readers of a row hit L1/L2),
// LDS = Ws + dacc/dvs only (~12.7KB) -> wave-capped 4 blocks/CU, grid gives ~3.
// acc compute sits BETWEEN the deg-atomic stream and its barrier so x-load latency
// overlaps other waves' deg atomics. FMA order identical to round-0 -> bit-identical.
__global__ __launch_bounds__(512, 8) void k_degxw(
        const int* __restrict__ gcursor, const uint2* __restrict__ barr,
        const float* __restrict__ x, const float* __restrict__ W,
        float* __restrict__ dinv,
        __half* __restrict__ xwhA, __half* __restrict__ xwhB) {
    __shared__ float Ws[NF * EM];     // 10.2 KB
    __shared__ float dacc[128];
    __shared__ float dvs[128];
    int bk = blockIdx.x, tid = threadIdx.x;
    if (tid < 128) dacc[tid] = 0.f;
    for (int i = tid; i < NF * EM; i += 512) Ws[i] = W[i];
    __syncthreads();   // Ws ready, dacc zeroed
    int base = bk * 128;
    // stream bucket records: weighted degree via LDS atomics (~8 records/thread)
    int cntb = min(gcursor[bk], CAPB);
    const uint2* row = barr + (size_t)bk * CAPB;
    for (int i = tid; i < cntb; i += 512) {
        uint2 r = row[i];
        atomicAdd(&dacc[r.x & 127u], __uint_as_float(r.y));
    }
    // xw accumulate for local nodes while other waves finish their deg atomics.
    // thread = (node, 5-dim group); x row from global; W broadcast from LDS.
    int n = tid & 127;
    int jg = tid >> 7;        // 0..3 -> dims jg*5..jg*5+4
    int j0 = jg * 5;
    int node = base + n;
    float acc[5] = {0.f, 0.f, 0.f, 0.f, 0.f};
    if (node < NN) {
        const float4* xr = (const float4*)(x + (size_t)node * NF);
        for (int k4 = 0; k4 < NF / 4; ++k4) {
            float4 xc = xr[k4];
            const float* wr = Ws + (k4 * 4) * EM + j0;
#pragma unroll
            for (int jj = 0; jj < 5; ++jj) acc[jj] = fmaf(xc.x, wr[jj], acc[jj]);
            wr += EM;
#pragma unroll
            for (int jj = 0; jj < 5; ++jj) acc[jj] = fmaf(xc.y, wr[jj], acc[jj]);
            wr += EM;
#pragma unroll
            for (int jj = 0; jj < 5; ++jj) acc[jj] = fmaf(xc.z, wr[jj], acc[jj]);
            wr += EM;
#pragma unroll
            for (int jj = 0; jj < 5; ++jj) acc[jj] = fmaf(xc.w, wr[jj], acc[jj]);
        }
    }
    __syncthreads();   // all deg atomics complete
    if (tid < 128) {
        float dv = rsqrtf(1.0f + dacc[tid]);   // +1 = self-loop
        dvs[tid] = dv;
        int gd = base + tid;
        if (gd < NN) dinv[gd] = dv;            // for sortaggr's epilogue
    }
    __syncthreads();
    if (node < NN) {
        float dv = dvs[n];
#pragma unroll
        for (int jj = 0; jj < 5; ++jj) {
            int j = j0 + jj;
            __half hv = __float2half(acc[jj] * dv);
            if (j < 16) xwhA[(size_t)node * 16 + j] = hv;
            else        xwhB[(size_t)node * 4 + (j - 16)] = hv;
        }
    }
}

__device__ inline void unpack16(uint4 a0, uint4 a1, float* f) {
    const __half2* h = (const __half2*)&a0;
#pragma unroll
    for (int c = 0; c < 4; ++c) { float2 t = __half22float2(h[c]); f[2*c] = t.x; f[2*c+1] = t.y; }
    h = (const __half2*)&a1;
#pragma unroll
    for (int c = 0; c < 4; ++c) { float2 t = __half22float2(h[c]); f[8+2*c] = t.x; f[9+2*c] = t.y; }
}
__device__ inline void unpack4(uint2 b0, float* f) {
    const __half2* h = (const __half2*)&b0;
#pragma unroll
    for (int c = 0; c < 2; ++c) { float2 t = __half22float2(h[c]); f[2*c] = t.x; f[2*c+1] = t.y; }
}

// ---------------- fused: LDS dl-sort + gather-aggregate + epilogue (round-0 proven) ----
__global__ void k_sortaggr(const int* __restrict__ gcursor,
                           const unsigned long long* __restrict__ barr64,
                           const __half* __restrict__ xwhA, const __half* __restrict__ xwhB,
                           const float* __restrict__ dinv, const float* __restrict__ b,
                           float* __restrict__ embed) {
    __shared__ unsigned long long srt[CAPB];   // 36.9 KB
    __shared__ unsigned int cnt[128];
    __shared__ unsigned int off[128];
    __shared__ unsigned int wtot;
    int bk = blockIdx.x, tid = threadIdx.x;
    if (tid < 128) cnt[tid] = 0;
    __syncthreads();
    int cntb = min(gcursor[bk], CAPB);
    const unsigned long long* row = barr64 + (size_t)bk * CAPB;
    unsigned long long rec[9];
    unsigned int pos[9];
    int K = 0;
    for (int e = tid; e < cntb; e += 512) {
        rec[K] = row[e];
        pos[K] = atomicAdd(&cnt[(unsigned)rec[K] & 127u], 1u);
        ++K;
    }
    __syncthreads();
    // inclusive scan of cnt[0..128) via two-wave shfl
    unsigned int v = 0, s = 0;
    if (tid < 128) {
        v = cnt[tid]; s = v;
#pragma unroll
        for (int o = 1; o < 64; o <<= 1) {
            unsigned int t = __shfl_up(s, o);
            if ((tid & 63) >= o) s += t;
        }
        if (tid == 63) wtot = s;
    }
    __syncthreads();
    if (tid < 128) {
        if (tid >= 64) s += wtot;
        off[tid] = s;              // inclusive end of run
    }
    __syncthreads();
    // scatter into sorted LDS order
    for (int k = 0; k < K; ++k) {
        unsigned int dl = (unsigned)rec[k] & 127u;
        srt[off[dl] - cnt[dl] + pos[k]] = rec[k];
    }
    __syncthreads();
    // aggregate: 4 threads per dst, records from LDS, gathers from split plane
    int d = tid >> 2, sub = tid & 3;
    int s0 = (int)(off[d] - cnt[d]), s1 = (int)off[d];
    const uint4* pA = (const uint4*)xwhA;
    const uint2* pB = (const uint2*)xwhB;
    float acc[20];
#pragma unroll
    for (int j = 0; j < 20; ++j) acc[j] = 0.f;
    for (int e = s0 + sub; e < s1; e += 4) {
        unsigned long long r = srt[e];
        unsigned int sN = ((unsigned int)r) >> 7;
        float nw = __uint_as_float((unsigned int)(r >> 32));  // raw edge weight
        uint4 a0 = pA[(size_t)sN * 2];
        uint4 a1 = pA[(size_t)sN * 2 + 1];
        uint2 b0 = pB[sN];
        float f[20];
        unpack16(a0, a1, f);
        unpack4(b0, f + 16);
#pragma unroll
        for (int j = 0; j < 20; ++j) acc[j] = fmaf(f[j], nw, acc[j]);
    }
#pragma unroll
    for (int j = 0; j < 20; ++j) {
        acc[j] += __shfl_xor(acc[j], 1);
        acc[j] += __shfl_xor(acc[j], 2);
    }
    if (sub == 0) {
        int gd = bk * 128 + d;
        if (gd < NN) {
            float dv = dinv[gd];
            uint4 a0 = pA[(size_t)gd * 2];
            uint4 a1 = pA[(size_t)gd * 2 + 1];
            uint2 b0 = pB[gd];
            float xdh[20];
            unpack16(a0, a1, xdh);
            unpack4(b0, xdh + 16);   // = xw[gd][:]*dinv[gd]
            float r[20];
            float ss = 0.f;
#pragma unroll
            for (int j = 0; j < 20; ++j) {
                r[j] = dv * (acc[j] + xdh[j]) + b[j];
                ss = fmaf(r[j], r[j], ss);
            }
            float inv = 1.0f / fmaxf(sqrtf(ss), 1e-12f);
            float4 o4[5];
            float* o = (float*)o4;
#pragma unroll
            for (int j = 0; j < 20; ++j) {
                float e2 = r[j] * inv;
                o[j] = e2 > 0.f ? e2 : 0.f;
            }
            float4* eo = (float4*)(embed + (size_t)gd * EM);
#pragma unroll
            for (int c = 0; c < 5; ++c) eo[c] = o4[c];
        }
    }
}

// ---------------- per-graph pool (max+mean) + final linear ----------------
__device__ inline int lbound(const int* __restrict__ batch, int key) {
    int lo = 0, hi = NN;
    while (lo < hi) {
        int mid = (lo + hi) >> 1;
        if (batch[mid] < key) lo = mid + 1; else hi = mid;
    }
    return lo;
}

__global__ void k_poolfinal(const float* __restrict__ embed, const int* __restrict__ batch,
                            const float* __restrict__ lw, const float* __restrict__ lb,
                            float* __restrict__ out) {
    __shared__ float cross[4][40];
    __shared__ float pooled[40];
    int g = blockIdx.x;
    int s0 = lbound(batch, g), s1 = lbound(batch, g + 1);
    int cnt = s1 - s0;
    float mx[EM], sm[EM];
#pragma unroll
    for (int j = 0; j < EM; ++j) { mx[j] = 0.f; sm[j] = 0.f; }
    for (int n = s0 + threadIdx.x; n < s1; n += 256) {
        const float4* e = (const float4*)(embed + (size_t)n * EM);
#pragma unroll
        for (int c = 0; c < 5; ++c) {
            float4 v = e[c];
            int j = c * 4;
            mx[j+0] = fmaxf(mx[j+0], v.x); sm[j+0] += v.x;
            mx[j+1] = fmaxf(mx[j+1], v.y); sm[j+1] += v.y;
            mx[j+2] = fmaxf(mx[j+2], v.z); sm[j+2] += v.z;
            mx[j+3] = fmaxf(mx[j+3], v.w); sm[j+3] += v.w;
        }
    }
#pragma unroll
    for (int o = 32; o > 0; o >>= 1) {
#pragma unroll
        for (int j = 0; j < EM; ++j) {
            mx[j] = fmaxf(mx[j], __shfl_xor(mx[j], o));
            sm[j] += __shfl_xor(sm[j], o);
        }
    }
    int wave = threadIdx.x >> 6, lane = threadIdx.x & 63;
    if (lane == 0) {
#pragma unroll
        for (int j = 0; j < EM; ++j) { cross[wave][j] = mx[j]; cross[wave][EM + j] = sm[j]; }
    }
    __syncthreads();
    if (threadIdx.x < 40) {
        int j = threadIdx.x;
        float v = cross[0][j];
        if (j < EM) v = fmaxf(fmaxf(v, cross[1][j]), fmaxf(cross[2][j], cross[3][j]));
        else        v = v + cross[1][j] + cross[2][j] + cross[3][j];
        if (j >= EM) v *= 1.0f / fmaxf((float)cnt, 1.0f);
        pooled[j] = v;
    }
    __syncthreads();
    if (threadIdx.x < NC) {
        int c = threadIdx.x;
        float acc = lb[c];
#pragma unroll
        for (int j = 0; j < 2 * EM; ++j) acc = fmaf(pooled[j], lw[j * NC + c], acc);
        out[g * NC + c] = acc;
    }
}

static inline size_t align_up(size_t v) { return (v + 1023) & ~(size_t)1023; }

extern "C" void kernel_launch(void* const* d_in, const int* in_sizes, int n_in,
                              void* d_out, int out_size, void* d_ws, size_t ws_size,
                              hipStream_t stream) {
    const float* x     = (const float*)d_in[0];
    const int*   ei    = (const int*)d_in[1];
    const float* ew    = (const float*)d_in[2];
    const int*   batch = (const int*)d_in[3];
    const float* W     = (const float*)d_in[4];
    const float* b     = (const float*)d_in[5];
    const float* lw    = (const float*)d_in[6];
    const float* lb    = (const float*)d_in[7];
    float* out = (float*)d_out;

    char* ws = (char*)d_ws;
    int*    gcursor = (int*)ws;    ws += align_up(4096);
    float*  dinv    = (float*)ws;  ws += align_up((size_t)NN * 4);          // 400 KB
    __half* xwhA    = (__half*)ws; ws += align_up((size_t)NN * 16 * 2);     // 3.2 MB
    __half* xwhB    = (__half*)ws; ws += align_up((size_t)NN * 4 * 2);      // 0.8 MB
    float*  embed   = (float*)ws;  ws += align_up((size_t)NN * EM * 4);     // 8 MB
    uint2*  barr    = (uint2*)ws;                                           // 28.8 MB
    unsigned long long* barr64 = (unsigned long long*)barr;

    const int* srcp = ei;
    const int* dstp = ei + NE;

    (void)hipMemsetAsync(gcursor, 0, 4096, stream);
    k_scatter<<<(NE + T - 1) / T, SBLK, 0, stream>>>(srcp, dstp, ew, gcursor, barr);
    k_degxw<<<NB, 512, 0, stream>>>(gcursor, barr, x, W, dinv, xwhA, xwhB);
    k_sortaggr<<<NB, 512, 0, stream>>>(gcursor, barr64, xwhA, xwhB, dinv, b, embed);
    k_poolfinal<<<NG, 256, 0, stream>>>(embed, batch, lw, lb, out);
}

// Round 10
// 238.385 us; speedup vs baseline: 1.1024x; 1.1024x over previous
//
#include <hip/hip_runtime.h>
#include <hip/hip_fp16.h>

#define NN 100000   // nodes
#define NE 3200000  // edges
#define NF 128      // in features
#define EM 20       // embed
#define NC 10       // classes
#define NG 64       // graphs

#define NB 782      // dst buckets of 128 nodes
#define CAPB 4608   // per-bucket capacity (mean 4096, +8 sigma)
#define T 4096      // edges per scatter block
#define SBLK 1024   // scatter block threads
#define NXW 391     // xw blocks: 391*256 = 100096 >= NN nodes, 4 thr/node

// ---------------- FAT kernel: xw blocks (independent) + scatter blocks ----------------
// Blocks [0,NXW): unscaled fp32 xwf = x @ W  (no scatter dependency -> co-scheduled
// with scatter's latency-bound waves; removes the 51.2MB x-stream from the serial
// degxw pass). Blocks [NXW, ...): round-0 proven bucketed counting-sort scatter.
// LDS: one 52.3KB char block carved for scatter; xw branch aliases Ws onto it
// (branch is block-uniform -> no union inflation).
__global__ __launch_bounds__(SBLK) void k_scatfat(
        const int* __restrict__ src, const int* __restrict__ dst,
        const float* __restrict__ w, int* __restrict__ gcursor,
        uint2* __restrict__ barr,
        const float* __restrict__ x, const float* __restrict__ W,
        float* __restrict__ xwf) {
    __shared__ __align__(16) char smem[52352];
    int tid = threadIdx.x;

    if (blockIdx.x < NXW) {
        // ---------------- xw branch: 4 threads/node, 5 dims each ----------------
        float* Ws = (float*)smem;                       // 10.2 KB
        for (int i = tid; i < NF * EM; i += SBLK) Ws[i] = W[i];
        __syncthreads();
        int node = blockIdx.x * 256 + (tid >> 2);
        int j0 = (tid & 3) * 5;
        if (node >= NN) return;
        float acc[5] = {0.f, 0.f, 0.f, 0.f, 0.f};
        const float4* xr = (const float4*)(x + (size_t)node * NF);
        for (int k4 = 0; k4 < NF / 4; ++k4) {           // ascending-k FMA order (round-0)
            float4 xc = xr[k4];
            const float* wr = Ws + (k4 * 4) * EM + j0;
#pragma unroll
            for (int jj = 0; jj < 5; ++jj) acc[jj] = fmaf(xc.x, wr[jj], acc[jj]);
            wr += EM;
#pragma unroll
            for (int jj = 0; jj < 5; ++jj) acc[jj] = fmaf(xc.y, wr[jj], acc[jj]);
            wr += EM;
#pragma unroll
            for (int jj = 0; jj < 5; ++jj) acc[jj] = fmaf(xc.z, wr[jj], acc[jj]);
            wr += EM;
#pragma unroll
            for (int jj = 0; jj < 5; ++jj) acc[jj] = fmaf(xc.w, wr[jj], acc[jj]);
        }
        float* o = xwf + (size_t)node * EM + j0;
#pragma unroll
        for (int jj = 0; jj < 5; ++jj) o[jj] = acc[jj];
        return;
    }

    // ---------------- scatter branch (round-0 proven, smem-carved) ----------------
    unsigned int* cnt   = (unsigned int*)smem;                  // 1024*4 @ 0
    unsigned int* off   = (unsigned int*)(smem + 4096);         // 1024*4 @ 4096
    unsigned int* gbase = (unsigned int*)(smem + 8192);         // NB*4   @ 8192
    unsigned int* wsum  = (unsigned int*)(smem + 11320);        // 16*4   @ 11320
    uint2*        staged= (uint2*)(smem + 11384);               // 4096*8 @ 11384 (8-aligned)
    unsigned short* bkt = (unsigned short*)(smem + 44152);      // 4096*2 @ 44152

    long E0 = (long)(blockIdx.x - NXW) * T;
    int tot = (int)min((long)T, (long)NE - E0);
    cnt[tid] = 0;
    __syncthreads();
    // histogram; cache dst in VGPRs
    unsigned int dreg[T / SBLK];
#pragma unroll
    for (int k = 0; k < T / SBLK; ++k) {
        int e = k * SBLK + tid;
        dreg[k] = 0;
        if (e < tot) {
            dreg[k] = (unsigned)dst[E0 + e];
            atomicAdd(&cnt[dreg[k] >> 7], 1u);
        }
    }
    __syncthreads();
    // exclusive scan of cnt[0..1024) via wave shfl
    {
        int lane = tid & 63, wv = tid >> 6;
        unsigned int v = cnt[tid];
        unsigned int s = v;
#pragma unroll
        for (int o = 1; o < 64; o <<= 1) {
            unsigned int t = __shfl_up(s, o);
            if (lane >= o) s += t;
        }
        if (lane == 63) wsum[wv] = s;
        __syncthreads();
        if (tid == 0) {
            unsigned int a = 0;
#pragma unroll
            for (int i = 0; i < 16; ++i) { unsigned int t = wsum[i]; wsum[i] = a; a += t; }
        }
        __syncthreads();
        off[tid] = wsum[wv] + s - v;   // exclusive prefix
    }
    __syncthreads();
    // reserve global segments; reset cnt as running slot counter
    if (tid < NB) {
        unsigned int c = cnt[tid];
        gbase[tid] = c ? (unsigned int)atomicAdd(&gcursor[tid], (int)c) : 0u;
        cnt[tid] = 0;
    }
    __syncthreads();
    // stage records grouped by bucket
#pragma unroll
    for (int k = 0; k < T / SBLK; ++k) {
        int e = k * SBLK + tid;
        if (e < tot) {
            long ge = E0 + e;
            unsigned int d = dreg[k];
            unsigned int b = d >> 7;
            unsigned int slot = atomicAdd(&cnt[b], 1u);
            unsigned int pos = off[b] + slot;
            staged[pos] = make_uint2((((unsigned)src[ge]) << 7) | (d & 127u),
                                     __float_as_uint(w[ge]));
            bkt[pos] = (unsigned short)b;
        }
    }
    __syncthreads();
    // coalesced run-flush
    for (int i = tid; i < tot; i += SBLK) {
        unsigned int b = bkt[i];
        unsigned int gpos = gbase[b] + ((unsigned)i - off[b]);
        if (gpos < CAPB) barr[(size_t)b * CAPB + gpos] = staged[i];
    }
}

// ---------------- deg (LDS atomics, = proven degb) + prescale (= proven r4 phase-2) ----
__global__ __launch_bounds__(1024) void k_degps(
        const int* __restrict__ gcursor, const uint2* __restrict__ barr,
        const float* xwf, float* __restrict__ dinv,
        __half* __restrict__ xwhA, __half* __restrict__ xwhB) {
    __shared__ float dacc[128];
    __shared__ float dvs[128];
    int bk = blockIdx.x, tid = threadIdx.x;
    if (tid < 128) dacc[tid] = 0.f;
    __syncthreads();
    int cntb = min(gcursor[bk], CAPB);
    const uint2* row = barr + (size_t)bk * CAPB;
    for (int i = tid; i < cntb; i += 1024) {
        uint2 r = row[i];
        atomicAdd(&dacc[r.x & 127u], __uint_as_float(r.y));
    }
    __syncthreads();
    if (tid < 128) {
        float dv = rsqrtf(1.0f + dacc[tid]);   // +1 = self-loop
        dvs[tid] = dv;
        int gd = bk * 128 + tid;
        if (gd < NN) dinv[gd] = dv;            // for sortaggr's epilogue
    }
    __syncthreads();
    // prescale this bucket's 128 nodes: fp16 planes = xwf * dinv (single fp16 rounding)
    for (int i = tid; i < 128 * EM; i += 1024) {
        int n = i / EM, dim = i - n * EM;
        int gd = bk * 128 + n;
        if (gd < NN) {
            __half hv = __float2half(xwf[(size_t)gd * EM + dim] * dvs[n]);
            if (dim < 16) xwhA[(size_t)gd * 16 + dim] = hv;
            else          xwhB[(size_t)gd * 4 + (dim - 16)] = hv;
        }
    }
}

__device__ inline void unpack16(uint4 a0, uint4 a1, float* f) {
    const __half2* h = (const __half2*)&a0;
#pragma unroll
    for (int c = 0; c < 4; ++c) { float2 t = __half22float2(h[c]); f[2*c] = t.x; f[2*c+1] = t.y; }
    h = (const __half2*)&a1;
#pragma unroll
    for (int c = 0; c < 4; ++c) { float2 t = __half22float2(h[c]); f[8+2*c] = t.x; f[9+2*c] = t.y; }
}
__device__ inline void unpack4(uint2 b0, float* f) {
    const __half2* h = (const __half2*)&b0;
#pragma unroll
    for (int c = 0; c < 2; ++c) { float2 t = __half22float2(h[c]); f[2*c] = t.x; f[2*c+1] = t.y; }
}

// ---------------- fused: LDS dl-sort + gather-aggregate + epilogue (round-0 proven) ----
__global__ void k_sortaggr(const int* __restrict__ gcursor,
                           const unsigned long long* __restrict__ barr64,
                           const __half* __restrict__ xwhA, const __half* __restrict__ xwhB,
                           const float* __restrict__ dinv, const float* __restrict__ b,
                           float* embed) {
    __shared__ unsigned long long srt[CAPB];   // 36.9 KB
    __shared__ unsigned int cnt[128];
    __shared__ unsigned int off[128];
    __shared__ unsigned int wtot;
    int bk = blockIdx.x, tid = threadIdx.x;
    if (tid < 128) cnt[tid] = 0;
    __syncthreads();
    int cntb = min(gcursor[bk], CAPB);
    const unsigned long long* row = barr64 + (size_t)bk * CAPB;
    unsigned long long rec[9];
    unsigned int pos[9];
    int K = 0;
    for (int e = tid; e < cntb; e += 512) {
        rec[K] = row[e];
        pos[K] = atomicAdd(&cnt[(unsigned)rec[K] & 127u], 1u);
        ++K;
    }
    __syncthreads();
    // inclusive scan of cnt[0..128) via two-wave shfl
    unsigned int v = 0, s = 0;
    if (tid < 128) {
        v = cnt[tid]; s = v;
#pragma unroll
        for (int o = 1; o < 64; o <<= 1) {
            unsigned int t = __shfl_up(s, o);
            if ((tid & 63) >= o) s += t;
        }
        if (tid == 63) wtot = s;
    }
    __syncthreads();
    if (tid < 128) {
        if (tid >= 64) s += wtot;
        off[tid] = s;              // inclusive end of run
    }
    __syncthreads();
    // scatter into sorted LDS order
    for (int k = 0; k < K; ++k) {
        unsigned int dl = (unsigned)rec[k] & 127u;
        srt[off[dl] - cnt[dl] + pos[k]] = rec[k];
    }
    __syncthreads();
    // aggregate: 4 threads per dst, records from LDS, gathers from split plane
    int d = tid >> 2, sub = tid & 3;
    int s0 = (int)(off[d] - cnt[d]), s1 = (int)off[d];
    const uint4* pA = (const uint4*)xwhA;
    const uint2* pB = (const uint2*)xwhB;
    float acc[20];
#pragma unroll
    for (int j = 0; j < 20; ++j) acc[j] = 0.f;
    for (int e = s0 + sub; e < s1; e += 4) {
        unsigned long long r = srt[e];
        unsigned int sN = ((unsigned int)r) >> 7;
        float nw = __uint_as_float((unsigned int)(r >> 32));  // raw edge weight
        uint4 a0 = pA[(size_t)sN * 2];
        uint4 a1 = pA[(size_t)sN * 2 + 1];
        uint2 b0 = pB[sN];
        float f[20];
        unpack16(a0, a1, f);
        unpack4(b0, f + 16);
#pragma unroll
        for (int j = 0; j < 20; ++j) acc[j] = fmaf(f[j], nw, acc[j]);
    }
#pragma unroll
    for (int j = 0; j < 20; ++j) {
        acc[j] += __shfl_xor(acc[j], 1);
        acc[j] += __shfl_xor(acc[j], 2);
    }
    if (sub == 0) {
        int gd = bk * 128 + d;
        if (gd < NN) {
            float dv = dinv[gd];
            uint4 a0 = pA[(size_t)gd * 2];
            uint4 a1 = pA[(size_t)gd * 2 + 1];
            uint2 b0 = pB[gd];
            float xdh[20];
            unpack16(a0, a1, xdh);
            unpack4(b0, xdh + 16);   // = xw[gd][:]*dinv[gd]
            float r[20];
            float ss = 0.f;
#pragma unroll
            for (int j = 0; j < 20; ++j) {
                r[j] = dv * (acc[j] + xdh[j]) + b[j];
                ss = fmaf(r[j], r[j], ss);
            }
            float inv = 1.0f / fmaxf(sqrtf(ss), 1e-12f);
            float4 o4[5];
            float* o = (float*)o4;
#pragma unroll
            for (int j = 0; j < 20; ++j) {
                float e2 = r[j] * inv;
                o[j] = e2 > 0.f ? e2 : 0.f;
            }
            float4* eo = (float4*)(embed + (size_t)gd * EM);
#pragma unroll
            for (int c = 0; c < 5; ++c) eo[c] = o4[c];
        }
    }
}

// ---------------- per-graph pool (max+mean) + final linear ----------------
__device__ inline int lbound(const int* __restrict__ batch, int key) {
    int lo = 0, hi = NN;
    while (lo < hi) {
        int mid = (lo + hi) >> 1;
        if (batch[mid] < key) lo = mid + 1; else hi = mid;
    }
    return lo;
}

__global__ void k_poolfinal(const float* __restrict__ embed, const int* __restrict__ batch,
                            const float* __restrict__ lw, const float* __restrict__ lb,
                            float* __restrict__ out) {
    __shared__ float cross[4][40];
    __shared__ float pooled[40];
    int g = blockIdx.x;
    int s0 = lbound(batch, g), s1 = lbound(batch, g + 1);
    int cnt = s1 - s0;
    float mx[EM], sm[EM];
#pragma unroll
    for (int j = 0; j < EM; ++j) { mx[j] = 0.f; sm[j] = 0.f; }
    for (int n = s0 + threadIdx.x; n < s1; n += 256) {
        const float4* e = (const float4*)(embed + (size_t)n * EM);
#pragma unroll
        for (int c = 0; c < 5; ++c) {
            float4 v = e[c];
            int j = c * 4;
            mx[j+0] = fmaxf(mx[j+0], v.x); sm[j+0] += v.x;
            mx[j+1] = fmaxf(mx[j+1], v.y); sm[j+1] += v.y;
            mx[j+2] = fmaxf(mx[j+2], v.z); sm[j+2] += v.z;
            mx[j+3] = fmaxf(mx[j+3], v.w); sm[j+3] += v.w;
        }
    }
#pragma unroll
    for (int o = 32; o > 0; o >>= 1) {
#pragma unroll
        for (int j = 0; j < EM; ++j) {
            mx[j] = fmaxf(mx[j], __shfl_xor(mx[j], o));
            sm[j] += __shfl_xor(sm[j], o);
        }
    }
    int wave = threadIdx.x >> 6, lane = threadIdx.x & 63;
    if (lane == 0) {
#pragma unroll
        for (int j = 0; j < EM; ++j) { cross[wave][j] = mx[j]; cross[wave][EM + j] = sm[j]; }
    }
    __syncthreads();
    if (threadIdx.x < 40) {
        int j = threadIdx.x;
        float v = cross[0][j];
        if (j < EM) v = fmaxf(fmaxf(v, cross[1][j]), fmaxf(cross[2][j], cross[3][j]));
        else        v = v + cross[1][j] + cross[2][j] + cross[3][j];
        if (j >= EM) v *= 1.0f / fmaxf((float)cnt, 1.0f);
        pooled[j] = v;
    }
    __syncthreads();
    if (threadIdx.x < NC) {
        int c = threadIdx.x;
        float acc = lb[c];
#pragma unroll
        for (int j = 0; j < 2 * EM; ++j) acc = fmaf(pooled[j], lw[j * NC + c], acc);
        out[g * NC + c] = acc;
    }
}

static inline size_t align_up(size_t v) { return (v + 1023) & ~(size_t)1023; }

extern "C" void kernel_launch(void* const* d_in, const int* in_sizes, int n_in,
                              void* d_out, int out_size, void* d_ws, size_t ws_size,
                              hipStream_t stream) {
    const float* x     = (const float*)d_in[0];
    const int*   ei    = (const int*)d_in[1];
    const float* ew    = (const float*)d_in[2];
    const int*   batch = (const int*)d_in[3];
    const float* W     = (const float*)d_in[4];
    const float* b     = (const float*)d_in[5];
    const float* lw    = (const float*)d_in[6];
    const float* lb    = (const float*)d_in[7];
    float* out = (float*)d_out;

    char* ws = (char*)d_ws;
    int*    gcursor = (int*)ws;    ws += align_up(4096);
    float*  dinv    = (float*)ws;  ws += align_up((size_t)NN * 4);          // 400 KB
    __half* xwhA    = (__half*)ws; ws += align_up((size_t)NN * 16 * 2);     // 3.2 MB
    __half* xwhB    = (__half*)ws; ws += align_up((size_t)NN * 4 * 2);      // 0.8 MB
    float*  xwf     = (float*)ws;  ws += align_up((size_t)NN * EM * 4);     // 8 MB
    uint2*  barr    = (uint2*)ws;                                           // 28.8 MB
    unsigned long long* barr64 = (unsigned long long*)barr;
    float*  embed   = xwf;   // alias: xwf dead after k_degps (kernel-boundary ordered)

    const int* srcp = ei;
    const int* dstp = ei + NE;

    (void)hipMemsetAsync(gcursor, 0, 4096, stream);
    k_scatfat<<<NXW + (NE + T - 1) / T, SBLK, 0, stream>>>(srcp, dstp, ew, gcursor, barr,
                                                           x, W, xwf);
    k_degps<<<NB, 1024, 0, stream>>>(gcursor, barr, xwf, dinv, xwhA, xwhB);
    k_sortaggr<<<NB, 512, 0, stream>>>(gcursor, barr64, xwhA, xwhB, dinv, b, embed);
    k_poolfinal<<<NG, 256, 0, stream>>>(embed, batch, lw, lb, out);
}

// Round 11
// 232.269 us; speedup vs baseline: 1.1315x; 1.0263x over previous
//
#include <hip/hip_runtime.h>
#include <hip/hip_fp16.h>

#define NN 100000   // nodes
#define NE 3200000  // edges
#define NF 128      // in features
#define EM 20       // embed
#define NC 10       // classes
#define NG 64       // graphs

#define NB 782      // dst buckets of 128 nodes
#define CAPB 4608   // per-bucket capacity (mean 4096, +8 sigma)
#define T 4096      // edges per scatter block
#define SBLK 1024   // scatter block threads
#define NXW 391     // xw blocks: 391*256 = 100096 >= NN nodes, 4 thr/node
#define GSPAN 16    // graphs tracked in LDS pool table per block (128-node window spans ~2)

// ---------------- FAT kernel: xw blocks (independent) + scatter blocks (r10 proven) ----
__global__ __launch_bounds__(SBLK) void k_scatfat(
        const int* __restrict__ src, const int* __restrict__ dst,
        const float* __restrict__ w, int* __restrict__ gcursor,
        uint2* __restrict__ barr,
        const float* __restrict__ x, const float* __restrict__ W,
        float* __restrict__ xwf) {
    __shared__ __align__(16) char smem[52352];
    int tid = threadIdx.x;

    if (blockIdx.x < NXW) {
        // ---------------- xw branch: 4 threads/node, 5 dims each ----------------
        float* Ws = (float*)smem;                       // 10.2 KB
        for (int i = tid; i < NF * EM; i += SBLK) Ws[i] = W[i];
        __syncthreads();
        int node = blockIdx.x * 256 + (tid >> 2);
        int j0 = (tid & 3) * 5;
        if (node >= NN) return;
        float acc[5] = {0.f, 0.f, 0.f, 0.f, 0.f};
        const float4* xr = (const float4*)(x + (size_t)node * NF);
        for (int k4 = 0; k4 < NF / 4; ++k4) {           // ascending-k FMA order (round-0)
            float4 xc = xr[k4];
            const float* wr = Ws + (k4 * 4) * EM + j0;
#pragma unroll
            for (int jj = 0; jj < 5; ++jj) acc[jj] = fmaf(xc.x, wr[jj], acc[jj]);
            wr += EM;
#pragma unroll
            for (int jj = 0; jj < 5; ++jj) acc[jj] = fmaf(xc.y, wr[jj], acc[jj]);
            wr += EM;
#pragma unroll
            for (int jj = 0; jj < 5; ++jj) acc[jj] = fmaf(xc.z, wr[jj], acc[jj]);
            wr += EM;
#pragma unroll
            for (int jj = 0; jj < 5; ++jj) acc[jj] = fmaf(xc.w, wr[jj], acc[jj]);
        }
        float* o = xwf + (size_t)node * EM + j0;
#pragma unroll
        for (int jj = 0; jj < 5; ++jj) o[jj] = acc[jj];
        return;
    }

    // ---------------- scatter branch (round-0 proven, smem-carved) ----------------
    unsigned int* cnt   = (unsigned int*)smem;                  // 1024*4 @ 0
    unsigned int* off   = (unsigned int*)(smem + 4096);         // 1024*4 @ 4096
    unsigned int* gbase = (unsigned int*)(smem + 8192);         // NB*4   @ 8192
    unsigned int* wsum  = (unsigned int*)(smem + 11320);        // 16*4   @ 11320
    uint2*        staged= (uint2*)(smem + 11384);               // 4096*8 @ 11384 (8-aligned)
    unsigned short* bkt = (unsigned short*)(smem + 44152);      // 4096*2 @ 44152

    long E0 = (long)(blockIdx.x - NXW) * T;
    int tot = (int)min((long)T, (long)NE - E0);
    cnt[tid] = 0;
    __syncthreads();
    // histogram; cache dst in VGPRs
    unsigned int dreg[T / SBLK];
#pragma unroll
    for (int k = 0; k < T / SBLK; ++k) {
        int e = k * SBLK + tid;
        dreg[k] = 0;
        if (e < tot) {
            dreg[k] = (unsigned)dst[E0 + e];
            atomicAdd(&cnt[dreg[k] >> 7], 1u);
        }
    }
    __syncthreads();
    // exclusive scan of cnt[0..1024) via wave shfl
    {
        int lane = tid & 63, wv = tid >> 6;
        unsigned int v = cnt[tid];
        unsigned int s = v;
#pragma unroll
        for (int o = 1; o < 64; o <<= 1) {
            unsigned int t = __shfl_up(s, o);
            if (lane >= o) s += t;
        }
        if (lane == 63) wsum[wv] = s;
        __syncthreads();
        if (tid == 0) {
            unsigned int a = 0;
#pragma unroll
            for (int i = 0; i < 16; ++i) { unsigned int t = wsum[i]; wsum[i] = a; a += t; }
        }
        __syncthreads();
        off[tid] = wsum[wv] + s - v;   // exclusive prefix
    }
    __syncthreads();
    // reserve global segments; reset cnt as running slot counter
    if (tid < NB) {
        unsigned int c = cnt[tid];
        gbase[tid] = c ? (unsigned int)atomicAdd(&gcursor[tid], (int)c) : 0u;
        cnt[tid] = 0;
    }
    __syncthreads();
    // stage records grouped by bucket
#pragma unroll
    for (int k = 0; k < T / SBLK; ++k) {
        int e = k * SBLK + tid;
        if (e < tot) {
            long ge = E0 + e;
            unsigned int d = dreg[k];
            unsigned int b = d >> 7;
            unsigned int slot = atomicAdd(&cnt[b], 1u);
            unsigned int pos = off[b] + slot;
            staged[pos] = make_uint2((((unsigned)src[ge]) << 7) | (d & 127u),
                                     __float_as_uint(w[ge]));
            bkt[pos] = (unsigned short)b;
        }
    }
    __syncthreads();
    // coalesced run-flush
    for (int i = tid; i < tot; i += SBLK) {
        unsigned int b = bkt[i];
        unsigned int gpos = gbase[b] + ((unsigned)i - off[b]);
        if (gpos < CAPB) barr[(size_t)b * CAPB + gpos] = staged[i];
    }
}

// ---------------- deg (LDS atomics) + prescale (r10 proven) ----------------
__global__ __launch_bounds__(1024) void k_degps(
        const int* __restrict__ gcursor, const uint2* __restrict__ barr,
        const float* __restrict__ xwf, float* __restrict__ dinv,
        __half* __restrict__ xwhA, __half* __restrict__ xwhB) {
    __shared__ float dacc[128];
    __shared__ float dvs[128];
    int bk = blockIdx.x, tid = threadIdx.x;
    if (tid < 128) dacc[tid] = 0.f;
    __syncthreads();
    int cntb = min(gcursor[bk], CAPB);
    const uint2* row = barr + (size_t)bk * CAPB;
    for (int i = tid; i < cntb; i += 1024) {
        uint2 r = row[i];
        atomicAdd(&dacc[r.x & 127u], __uint_as_float(r.y));
    }
    __syncthreads();
    if (tid < 128) {
        float dv = rsqrtf(1.0f + dacc[tid]);   // +1 = self-loop
        dvs[tid] = dv;
        int gd = bk * 128 + tid;
        if (gd < NN) dinv[gd] = dv;            // for sortaggr's epilogue
    }
    __syncthreads();
    // prescale this bucket's 128 nodes: fp16 planes = xwf * dinv (single fp16 rounding)
    for (int i = tid; i < 128 * EM; i += 1024) {
        int n = i / EM, dim = i - n * EM;
        int gd = bk * 128 + n;
        if (gd < NN) {
            __half hv = __float2half(xwf[(size_t)gd * EM + dim] * dvs[n]);
            if (dim < 16) xwhA[(size_t)gd * 16 + dim] = hv;
            else          xwhB[(size_t)gd * 4 + (dim - 16)] = hv;
        }
    }
}

__device__ inline void unpack16(uint4 a0, uint4 a1, float* f) {
    const __half2* h = (const __half2*)&a0;
#pragma unroll
    for (int c = 0; c < 4; ++c) { float2 t = __half22float2(h[c]); f[2*c] = t.x; f[2*c+1] = t.y; }
    h = (const __half2*)&a1;
#pragma unroll
    for (int c = 0; c < 4; ++c) { float2 t = __half22float2(h[c]); f[8+2*c] = t.x; f[9+2*c] = t.y; }
}
__device__ inline void unpack4(uint2 b0, float* f) {
    const __half2* h = (const __half2*)&b0;
#pragma unroll
    for (int c = 0; c < 2; ++c) { float2 t = __half22float2(h[c]); f[2*c] = t.x; f[2*c+1] = t.y; }
}

// ---------------- fused: sort + gather-aggregate + epilogue + POOL (no embed array) ----
// Epilogue values are >=0 (post-ReLU) -> max pool via integer atomicMax on float bits.
// Per-block LDS pool table [GSPAN][20] (sum f32 + max i32 + cnt), flushed with <=320
// global atomics/block into a 10.5KB device table. 128 sorted-batch nodes span ~2
// graphs; GSPAN=16 with a direct-global fallback keeps correctness unconditional.
__global__ void k_sortaggr(const int* __restrict__ gcursor,
                           const unsigned long long* __restrict__ barr64,
                           const __half* __restrict__ xwhA, const __half* __restrict__ xwhB,
                           const float* __restrict__ dinv, const float* __restrict__ b,
                           const int* __restrict__ batch,
                           float* __restrict__ gsum, int* __restrict__ gmaxI,
                           int* __restrict__ gcnt) {
    __shared__ unsigned long long srt[CAPB];   // 36.9 KB
    __shared__ unsigned int cnt[128];
    __shared__ unsigned int off[128];
    __shared__ unsigned int wtot;
    __shared__ float lsum[GSPAN][EM];          // 1.28 KB
    __shared__ int   lmaxI[GSPAN][EM];         // 1.28 KB
    __shared__ int   lcnt[GSPAN];
    __shared__ int   gmin_s;
    int bk = blockIdx.x, tid = threadIdx.x;
    if (tid < 128) cnt[tid] = 0;
    for (int i = tid; i < GSPAN * EM; i += 512) { lsum[i / EM][i % EM] = 0.f; lmaxI[i / EM][i % EM] = 0; }
    if (tid < GSPAN) lcnt[tid] = 0;
    if (tid == 0) gmin_s = batch[bk * 128];
    __syncthreads();
    int cntb = min(gcursor[bk], CAPB);
    const unsigned long long* row = barr64 + (size_t)bk * CAPB;
    unsigned long long rec[9];
    unsigned int pos[9];
    int K = 0;
    for (int e = tid; e < cntb; e += 512) {
        rec[K] = row[e];
        pos[K] = atomicAdd(&cnt[(unsigned)rec[K] & 127u], 1u);
        ++K;
    }
    __syncthreads();
    // inclusive scan of cnt[0..128) via two-wave shfl
    unsigned int v = 0, s = 0;
    if (tid < 128) {
        v = cnt[tid]; s = v;
#pragma unroll
        for (int o = 1; o < 64; o <<= 1) {
            unsigned int t = __shfl_up(s, o);
            if ((tid & 63) >= o) s += t;
        }
        if (tid == 63) wtot = s;
    }
    __syncthreads();
    if (tid < 128) {
        if (tid >= 64) s += wtot;
        off[tid] = s;              // inclusive end of run
    }
    __syncthreads();
    // scatter into sorted LDS order
    for (int k = 0; k < K; ++k) {
        unsigned int dl = (unsigned)rec[k] & 127u;
        srt[off[dl] - cnt[dl] + pos[k]] = rec[k];
    }
    __syncthreads();
    // aggregate: 4 threads per dst, records from LDS, gathers from split plane
    int d = tid >> 2, sub = tid & 3;
    int s0 = (int)(off[d] - cnt[d]), s1 = (int)off[d];
    const uint4* pA = (const uint4*)xwhA;
    const uint2* pB = (const uint2*)xwhB;
    float acc[20];
#pragma unroll
    for (int j = 0; j < 20; ++j) acc[j] = 0.f;
    for (int e = s0 + sub; e < s1; e += 4) {
        unsigned long long r = srt[e];
        unsigned int sN = ((unsigned int)r) >> 7;
        float nw = __uint_as_float((unsigned int)(r >> 32));  // raw edge weight
        uint4 a0 = pA[(size_t)sN * 2];
        uint4 a1 = pA[(size_t)sN * 2 + 1];
        uint2 b0 = pB[sN];
        float f[20];
        unpack16(a0, a1, f);
        unpack4(b0, f + 16);
#pragma unroll
        for (int j = 0; j < 20; ++j) acc[j] = fmaf(f[j], nw, acc[j]);
    }
#pragma unroll
    for (int j = 0; j < 20; ++j) {
        acc[j] += __shfl_xor(acc[j], 1);
        acc[j] += __shfl_xor(acc[j], 2);
    }
    if (sub == 0) {
        int gd = bk * 128 + d;
        if (gd < NN) {
            float dv = dinv[gd];
            uint4 a0 = pA[(size_t)gd * 2];
            uint4 a1 = pA[(size_t)gd * 2 + 1];
            uint2 b0 = pB[gd];
            float xdh[20];
            unpack16(a0, a1, xdh);
            unpack4(b0, xdh + 16);   // = xw[gd][:]*dinv[gd]
            float r[20];
            float ss = 0.f;
#pragma unroll
            for (int j = 0; j < 20; ++j) {
                r[j] = dv * (acc[j] + xdh[j]) + b[j];
                ss = fmaf(r[j], r[j], ss);
            }
            float inv = 1.0f / fmaxf(sqrtf(ss), 1e-12f);
            float o[20];
#pragma unroll
            for (int j = 0; j < 20; ++j) {
                float e2 = r[j] * inv;
                o[j] = e2 > 0.f ? e2 : 0.f;   // >= 0: int-max pooling valid
            }
            int g = batch[gd];
            int gl = g - gmin_s;
            if (gl < GSPAN) {
#pragma unroll
                for (int j = 0; j < 20; ++j) {
                    atomicAdd(&lsum[gl][j], o[j]);
                    atomicMax(&lmaxI[gl][j], __float_as_int(o[j]));
                }
                atomicAdd(&lcnt[gl], 1);
            } else {   // never in practice (sorted batch); correctness fallback
#pragma unroll
                for (int j = 0; j < 20; ++j) {
                    atomicAdd(&gsum[g * EM + j], o[j]);
                    atomicMax(&gmaxI[g * EM + j], __float_as_int(o[j]));
                }
                atomicAdd(&gcnt[g], 1);
            }
        }
    }
    __syncthreads();
    // flush LDS pool table to global (<=320 atomics + 16 cnt atomics per block)
    for (int i = tid; i < GSPAN * EM; i += 512) {
        int gl = i / EM, j = i - gl * EM;
        int g = gmin_s + gl;
        if (g < NG && lcnt[gl] > 0) {
            atomicAdd(&gsum[g * EM + j], lsum[gl][j]);
            atomicMax(&gmaxI[g * EM + j], lmaxI[gl][j]);
        }
    }
    if (tid < GSPAN) {
        int g = gmin_s + tid;
        if (g < NG && lcnt[tid] > 0) atomicAdd(&gcnt[g], lcnt[tid]);
    }
}

// ---------------- final: pool table -> linear (one block per graph) ----------------
__global__ void k_final(const float* __restrict__ gsum, const int* __restrict__ gmaxI,
                        const int* __restrict__ gcnt,
                        const float* __restrict__ lw, const float* __restrict__ lb,
                        float* __restrict__ out) {
    __shared__ float pooled[2 * EM];
    int g = blockIdx.x, tid = threadIdx.x;
    if (tid < EM) pooled[tid] = __int_as_float(gmaxI[g * EM + tid]);   // empty graph -> 0
    else if (tid < 2 * EM) {
        float c = (float)gcnt[g];
        pooled[tid] = gsum[g * EM + (tid - EM)] / fmaxf(c, 1.0f);
    }
    __syncthreads();
    if (tid < NC) {
        float acc = lb[tid];
#pragma unroll
        for (int j = 0; j < 2 * EM; ++j) acc = fmaf(pooled[j], lw[j * NC + tid], acc);
        out[g * NC + tid] = acc;
    }
}

static inline size_t align_up(size_t v) { return (v + 1023) & ~(size_t)1023; }

extern "C" void kernel_launch(void* const* d_in, const int* in_sizes, int n_in,
                              void* d_out, int out_size, void* d_ws, size_t ws_size,
                              hipStream_t stream) {
    const float* x     = (const float*)d_in[0];
    const int*   ei    = (const int*)d_in[1];
    const float* ew    = (const float*)d_in[2];
    const int*   batch = (const int*)d_in[3];
    const float* W     = (const float*)d_in[4];
    const float* b     = (const float*)d_in[5];
    const float* lw    = (const float*)d_in[6];
    const float* lb    = (const float*)d_in[7];
    float* out = (float*)d_out;

    char* ws = (char*)d_ws;
    int*    gcursor = (int*)ws;    ws += align_up(4096);
    char*   poolws  = ws;          ws += align_up(5120 + 5120 + 256);       // 10.5 KB table
    float*  gsum    = (float*)poolws;
    int*    gmaxI   = (int*)(poolws + 5120);
    int*    gcnt    = (int*)(poolws + 10240);
    float*  dinv    = (float*)ws;  ws += align_up((size_t)NN * 4);          // 400 KB
    __half* xwhA    = (__half*)ws; ws += align_up((size_t)NN * 16 * 2);     // 3.2 MB
    __half* xwhB    = (__half*)ws; ws += align_up((size_t)NN * 4 * 2);      // 0.8 MB
    float*  xwf     = (float*)ws;  ws += align_up((size_t)NN * EM * 4);     // 8 MB
    uint2*  barr    = (uint2*)ws;                                           // 28.8 MB
    unsigned long long* barr64 = (unsigned long long*)barr;

    const int* srcp = ei;
    const int* dstp = ei + NE;

    // one memset covers gcursor + pool tables (contiguous carve)
    (void)hipMemsetAsync(gcursor, 0, align_up(4096) + align_up(10496), stream);
    k_scatfat<<<NXW + (NE + T - 1) / T, SBLK, 0, stream>>>(srcp, dstp, ew, gcursor, barr,
                                                           x, W, xwf);
    k_degps<<<NB, 1024, 0, stream>>>(gcursor, barr, xwf, dinv, xwhA, xwhB);
    k_sortaggr<<<NB, 512, 0, stream>>>(gcursor, barr64, xwhA, xwhB, dinv, b,
                                       batch, gsum, gmaxI, gcnt);
    k_final<<<NG, 64, 0, stream>>>(gsum, gmaxI, gcnt, lw, lb, out);
}